// Round 9
// baseline (413.205 us; speedup 1.0000x reference)
//
#include <hip/hip_runtime.h>

// LinkPredictionGNN: 2-layer GCN encode + dot-product decode.
// R8: k_bin rewritten as claim-then-direct-scatter -- per-bucket runs are
// claimed BEFORE the scatter (h[b] known from the count pass), so edges write
// straight to their global bucket run. Removes the 32KB LDS stage round-trip,
// the per-edge 9-iter binary search, one of two scans, and a barrier phase;
// LDS 43KB -> ~11KB (occupancy up). Run structure in binned[] is identical.
// k_detect slimmed to 512 samples; bcnt/gcur0 zeroing via hipMemsetAsync
// nodes. Decode untouched: L2-miss-path-bound at ~3 TB/s (291 MB / 95 us,
// stable across all measured rounds).

#define IC1 128   // input channels (= hidden channels for conv2 input)
#define OC1 128   // conv1 output channels
#define OC2 64    // conv2 output channels

#define BSH    9            // bucket shift: 512 nodes per bucket
#define BNODES (1 << BSH)
#define NBMAX  512          // supports N <= 262144 (N = 100000 here)
#define CHB    4096         // edges per k_bin block
#define CHH    4096         // edges per k_hist block
// binned pack: src in bits [0,20), d_local in bits [20,29)  (requires N < 2^20)

typedef unsigned int u32;
typedef unsigned short u16;
typedef __attribute__((ext_vector_type(8))) short short8v;   // 8 bf16 = 4 VGPR
typedef __attribute__((ext_vector_type(4))) float f32x4;

// ---- bf16 helpers (RNE pack, bit-shift unpack) ----
__device__ __forceinline__ u16 f2bf(float f) {
  u32 u = __float_as_uint(f);
  u32 r = (u + 0x7fffu + ((u >> 16) & 1u)) >> 16;
  return (u16)r;
}
__device__ __forceinline__ u32 pack2bf(float lo, float hi) {
  return (u32)f2bf(lo) | ((u32)f2bf(hi) << 16);
}
__device__ __forceinline__ float bflo(u32 w) { return __uint_as_float(w << 16); }
__device__ __forceinline__ float bfhi(u32 w) { return __uint_as_float(w & 0xffff0000u); }

// Edge-index element: int64 per reference, int32 possible per harness doc.
__device__ __forceinline__ int getIdx(const void* p, long long i, int is64) {
  return is64 ? (int)((const long long*)p)[i] : ((const int*)p)[i];
}

// dtype flag only (bcnt/gcur0 zeroed by async memset). 512 samples suffice:
// int32 data read as int64 exceeds n_nodes with P ~ 1 - (N/2^32)^512.
__global__ void k_detect(const void* pei, long long E, int n_nodes, int* flagbuf) {
  __shared__ int bad;
  if (threadIdx.x == 0) bad = 0;
  __syncthreads();
  long long cnt = E < 512 ? E : 512;
  const unsigned long long* p64 = (const unsigned long long*)pei;
  for (long long i = threadIdx.x; i < cnt; i += blockDim.x)
    if (p64[i] >= (unsigned long long)n_nodes) bad = 1;   // benign race
  __syncthreads();
  if (threadIdx.x == 0) flagbuf[0] = bad ? 0 : 1;
}

// Pure per-bucket edge histogram (LDS atomics only).
__global__ __launch_bounds__(256) void k_hist(const void* pei, long long E,
                                              const int* flagbuf, int* bcnt, int NB) {
  __shared__ int h[NBMAX];
  int f = flagbuf[0];
  for (int i = threadIdx.x; i < NB; i += 256) h[i] = 0;
  __syncthreads();
  long long e0 = (long long)blockIdx.x * CHH;
  long long e1 = min(E, e0 + CHH);
  for (long long e = e0 + threadIdx.x; e < e1; e += 256)
    atomicAdd(&h[getIdx(pei, E + e, f) >> BSH], 1);
  __syncthreads();
  for (int i = threadIdx.x; i < NB; i += 256)
    if (h[i]) atomicAdd(&bcnt[i], h[i]);
}

// Claim-then-direct-scatter partition. Bucket base offsets (prefix of the
// L2-hot bcnt) scanned in LDS; this block's per-bucket runs claimed up front
// via gcur0; edges then write DIRECTLY into their global bucket run (h[]
// recycled as the per-bucket scatter cursor). No LDS staging, no binary
// search, one scan, ~11KB LDS.
__global__ __launch_bounds__(256) void k_bin(const void* pei, long long E,
                                             const int* flagbuf, const int* bcnt,
                                             int* gcur0, u32* binned, int NB) {
  __shared__ int h[NBMAX], gstart[NBMAX], gboff[NBMAX];
  __shared__ int sa[256];
  __shared__ int carryS;
  int f = flagbuf[0];
  int tid = threadIdx.x;
  for (int i = tid; i < NB; i += 256) h[i] = 0;
  if (tid == 0) carryS = 0;
  __syncthreads();
  long long e0 = (long long)blockIdx.x * CHB;
  long long e1 = min(E, e0 + CHB);
  // pass 1: count this chunk's edges per bucket
  for (long long e = e0 + tid; e < e1; e += 256)
    atomicAdd(&h[getIdx(pei, E + e, f) >> BSH], 1);
  __syncthreads();
  // exclusive scan bcnt -> gboff (global bucket offsets; bcnt is L2-hot)
  for (int base = 0; base < NB; base += 256) {
    int i = base + tid;
    int v = (i < NB) ? bcnt[i] : 0;
    sa[tid] = v;
    __syncthreads();
    for (int off = 1; off < 256; off <<= 1) {
      int t = (tid >= off) ? sa[tid - off] : 0;
      __syncthreads();
      sa[tid] += t;
      __syncthreads();
    }
    int exc = sa[tid] - v + carryS;
    if (i < NB) gboff[i] = exc;
    __syncthreads();
    if (tid == 255) carryS += sa[255];
    __syncthreads();
  }
  // claim this block's run in each non-empty bucket; recycle h as cursor
  for (int b = tid; b < NB; b += 256) {
    int c = h[b];
    gstart[b] = c ? (gboff[b] + atomicAdd(&gcur0[b], c)) : 0;
    h[b] = 0;
  }
  __syncthreads();
  // pass 2: scatter directly into global bucket runs
  for (long long e = e0 + tid; e < e1; e += 256) {
    int s = getIdx(pei, e, f);
    int d = getIdx(pei, E + e, f);
    int b = d >> BSH;
    int ofs = atomicAdd(&h[b], 1);
    binned[(long long)gstart[b] + ofs] = (u32)s | ((u32)(d & (BNODES - 1)) << 20);
  }
}

// One block per bucket. Window base = block-reduce prefix of bcnt. Pass 1:
// LDS histogram of local dst -> deg -> dinv + rowst (coalesced). Pass 2:
// scatter bucket edges into the bucket's contiguous csr window.
__global__ __launch_bounds__(512) void k_fill2(const u32* __restrict__ binned,
                                               const int* __restrict__ bcnt,
                                               float* __restrict__ dinv,
                                               int* __restrict__ rowst,
                                               u32* __restrict__ csr, int N, int NB) {
  __shared__ int cnt[BNODES], sa[BNODES], sb[BNODES], cursor[BNODES];
  __shared__ int redu[8];
  __shared__ int baseS;
  int b = blockIdx.x;
  int v0 = b << BSH;
  int nv = min(BNODES, N - v0);
  int tid = threadIdx.x;
  // base = sum(bcnt[0..b))
  int part = 0;
  for (int i = tid; i < b; i += 512) part += bcnt[i];
  #pragma unroll
  for (int off = 32; off; off >>= 1) part += __shfl_down(part, off);
  if ((tid & 63) == 0) redu[tid >> 6] = part;
  for (int i = tid; i < BNODES; i += 512) cnt[i] = 0;
  __syncthreads();
  if (tid == 0) {
    int s = 0;
    #pragma unroll
    for (int w = 0; w < 8; ++w) s += redu[w];
    baseS = s;
  }
  __syncthreads();
  int base = baseS;
  int j1 = base + bcnt[b];
  for (int j = base + tid; j < j1; j += 512)
    atomicAdd(&cnt[binned[j] >> 20], 1);
  __syncthreads();
  sa[tid] = cnt[tid];
  __syncthreads();
  int* A = sa; int* B = sb;
  #pragma unroll 1
  for (int off = 1; off < BNODES; off <<= 1) {   // inclusive Hillis-Steele
    B[tid] = A[tid] + ((tid >= off) ? A[tid - off] : 0);
    __syncthreads();
    int* t = A; A = B; B = t;
  }
  if (tid < nv) {
    int c = cnt[tid];
    int exc = A[tid] - c;
    rowst[v0 + tid] = base + exc;
    cursor[tid] = exc;
    dinv[v0 + tid] = rsqrtf((float)(c + 1));   // + self-loop
  }
  if (b == NB - 1 && tid == 0) rowst[N] = j1;
  __syncthreads();
  for (int j = base + tid; j < j1; j += 512) {
    u32 u = binned[j];
    int p = atomicAdd(&cursor[u >> 20], 1);
    csr[base + p] = u & 0xFFFFFu;
  }
}

// Pre-transpose both weights -> bf16 Wt[c][k] (K contiguous per out column).
__global__ void k_prepw(const float* __restrict__ W1, const float* __restrict__ W2,
                        u16* __restrict__ Wt1, u16* __restrict__ Wt2) {
  int i = blockIdx.x * blockDim.x + threadIdx.x;
  if (i < 128 * OC1) {
    int k = i / OC1, c = i % OC1;
    Wt1[c * 128 + k] = f2bf(W1[i]);
  } else {
    int j = i - 128 * OC1;
    if (j < 128 * OC2) {
      int k = j / OC2, c = j % OC2;
      Wt2[c * 128 + k] = f2bf(W2[j]);
    }
  }
}

// t = x @ W via mfma_f32_16x16x32_bf16. 128-row x-tile in LDS (padded rows);
// B-fragments read directly from L1/L2-resident Wt (no LDS panel). 4 waves,
// wave = 32 rows (2 row-tiles), 2 MFMAs per B-frag load, 64 MFMA/wave.
// Layouts (R5-validated): A row=lane&15, k=(lane>>4)*8+j; B out-col=lane&15
// from K-contiguous Wt; C/D col=lane&15, row=(lane>>4)*4+reg.
template<int OC, bool BF16IN>
__global__ __launch_bounds__(256) void k_gemm_mfma(const void* __restrict__ xin,
                                                   const u16* __restrict__ Wt,
                                                   u16* __restrict__ t, int N) {
  constexpr int CT = OC / 16;       // col tiles (8 or 4)
  constexpr int LW = 136;           // padded LDS row (bf16): 272B stride
  __shared__ u16 xs[128][LW];
  const int tid = threadIdx.x;
  const int lane = tid & 63, wv = tid >> 6;
  const long long rowBase = (long long)blockIdx.x * 128;

  if constexpr (BF16IN) {
    const u16* xg = (const u16*)xin;
    #pragma unroll
    for (int i = tid; i < 128 * 16; i += 256) {    // 16B chunks
      int r = i >> 4, c = i & 15;
      uint4 v = make_uint4(0u, 0u, 0u, 0u);
      if (rowBase + r < N) v = ((const uint4*)(xg + (rowBase + r) * IC1))[c];
      *(uint4*)&xs[r][c * 8] = v;
    }
  } else {
    const float* xg = (const float*)xin;
    #pragma unroll
    for (int i = tid; i < 128 * 16; i += 256) {
      int r = i >> 4, c = i & 15;
      uint4 o = make_uint4(0u, 0u, 0u, 0u);
      if (rowBase + r < N) {
        const float4* src = (const float4*)(xg + (rowBase + r) * IC1 + c * 8);
        float4 a = src[0], bq = src[1];
        o.x = pack2bf(a.x, a.y);  o.y = pack2bf(a.z, a.w);
        o.z = pack2bf(bq.x, bq.y); o.w = pack2bf(bq.z, bq.w);
      }
      *(uint4*)&xs[r][c * 8] = o;
    }
  }
  __syncthreads();

  const int frow = lane & 15, fk = (lane >> 4) * 8;
  short8v a[2][4];
  #pragma unroll
  for (int rt = 0; rt < 2; ++rt)
    #pragma unroll
    for (int kq = 0; kq < 4; ++kq)
      a[rt][kq] = *(const short8v*)&xs[wv * 32 + rt * 16 + frow][kq * 32 + fk];

  f32x4 acc[2][CT];
  #pragma unroll
  for (int ct = 0; ct < CT; ++ct) {
    acc[0][ct] = (f32x4){0.f, 0.f, 0.f, 0.f};
    acc[1][ct] = (f32x4){0.f, 0.f, 0.f, 0.f};
    #pragma unroll
    for (int kq = 0; kq < 4; ++kq) {
      short8v bfrag = *(const short8v*)(Wt + (ct * 16 + frow) * 128 + kq * 32 + fk);
      acc[0][ct] = __builtin_amdgcn_mfma_f32_16x16x32_bf16(a[0][kq], bfrag, acc[0][ct], 0, 0, 0);
      acc[1][ct] = __builtin_amdgcn_mfma_f32_16x16x32_bf16(a[1][kq], bfrag, acc[1][ct], 0, 0, 0);
    }
  }

  const int crow0 = (lane >> 4) * 4, ccol = lane & 15;
  #pragma unroll
  for (int rt = 0; rt < 2; ++rt)
    #pragma unroll
    for (int ct = 0; ct < CT; ++ct)
      #pragma unroll
      for (int r = 0; r < 4; ++r) {
        long long row = rowBase + wv * 32 + rt * 16 + crow0 + r;
        if (row < N) t[row * OC + ct * 16 + ccol] = f2bf(acc[rt][ct][r]);
      }
}

// out[v] = sum_{e: dst=v} t[src_e]*w_e + t[v]*dinv[v]^2 + bias (optional relu)
// One wave per node; G=CH/8 lanes per row (16B bf16x8 per lane), EPI=64/G
// edges gathered per iteration. w = dinv[s]*dinv[v] from L2-hot dinv table.
template<int CH>
__global__ __launch_bounds__(256) void k_agg(const u16* __restrict__ t,
                                             u16* __restrict__ out,
                                             const float* __restrict__ dinv,
                                             const int* __restrict__ rowst,
                                             const u32* __restrict__ csr,
                                             const float* __restrict__ bias,
                                             int N, int relu) {
  constexpr int G   = CH / 8;   // lanes per edge row (16 or 8)
  constexpr int EPI = 64 / G;   // edges per iteration (4 or 8)
  long long wid = ((long long)blockIdx.x * blockDim.x + threadIdx.x) >> 6;
  int lane = threadIdx.x & 63;
  if (wid >= N) return;
  int v = (int)wid;
  int sub = lane / G;           // edge slot
  int cl  = lane % G;           // 16B chunk within row
  float dv = dinv[v];
  float selfw = (sub == 0) ? dv * dv : 0.f;
  float acc[8];
  {
    uint4 u = ((const uint4*)(t + (long long)v * CH))[cl];
    acc[0] = bflo(u.x) * selfw; acc[1] = bfhi(u.x) * selfw;
    acc[2] = bflo(u.y) * selfw; acc[3] = bfhi(u.y) * selfw;
    acc[4] = bflo(u.z) * selfw; acc[5] = bfhi(u.z) * selfw;
    acc[6] = bflo(u.w) * selfw; acc[7] = bfhi(u.w) * selfw;
  }
  int st = rowst[v];
  int cnt = rowst[v + 1] - st;
  for (int base = 0; base < cnt; base += 64) {
    int m = min(64, cnt - base);
    int s = 0; float w = 0.f;
    if (lane < m) { s = (int)csr[st + base + lane]; w = dinv[s] * dv; }
    int iters = (m + EPI - 1) / EPI;
    #pragma unroll 4
    for (int j = 0; j < iters; ++j) {
      int src  = __shfl(s, j * EPI + sub);   // padded lanes give s=0,w=0
      float ww = __shfl(w, j * EPI + sub);
      uint4 u = ((const uint4*)(t + (long long)src * CH))[cl];
      acc[0] += bflo(u.x) * ww; acc[1] += bfhi(u.x) * ww;
      acc[2] += bflo(u.y) * ww; acc[3] += bfhi(u.y) * ww;
      acc[4] += bflo(u.z) * ww; acc[5] += bfhi(u.z) * ww;
      acc[6] += bflo(u.w) * ww; acc[7] += bfhi(u.w) * ww;
    }
  }
  #pragma unroll
  for (int off = G; off < 64; off <<= 1) {
    #pragma unroll
    for (int i = 0; i < 8; ++i) acc[i] += __shfl_xor(acc[i], off);
  }
  if (sub == 0) {
    float4 b0 = ((const float4*)bias)[cl * 2];
    float4 b1 = ((const float4*)bias)[cl * 2 + 1];
    float o[8] = {acc[0] + b0.x, acc[1] + b0.y, acc[2] + b0.z, acc[3] + b0.w,
                  acc[4] + b1.x, acc[5] + b1.y, acc[6] + b1.z, acc[7] + b1.w};
    if (relu) {
      #pragma unroll
      for (int i = 0; i < 8; ++i) o[i] = fmaxf(o[i], 0.f);
    }
    uint4 w4;
    w4.x = pack2bf(o[0], o[1]); w4.y = pack2bf(o[2], o[3]);
    w4.z = pack2bf(o[4], o[5]); w4.w = pack2bf(o[6], o[7]);
    ((uint4*)(out + (long long)v * CH))[cl] = w4;
  }
}

// pred[e] = dot(z[src_e], z[dst_e]) over 64 bf16 ch. 8 lanes/edge, 16B/lane.
__global__ __launch_bounds__(256) void k_decode(const u16* __restrict__ z,
                                                const void* pei, const void* nei,
                                                float* __restrict__ out,
                                                long long E, const int* flagbuf) {
  int f = flagbuf[0];
  long long g = ((long long)blockIdx.x * blockDim.x + threadIdx.x) >> 3;
  int wi = threadIdx.x & 7;
  if (g >= 2 * E) return;
  const void* ei = (g < E) ? pei : nei;
  long long e = (g < E) ? g : g - E;
  int s = getIdx(ei, e, f);
  int d = getIdx(ei, E + e, f);
  uint4 a = ((const uint4*)(z + (long long)s * OC2))[wi];
  uint4 b = ((const uint4*)(z + (long long)d * OC2))[wi];
  float p = bflo(a.x) * bflo(b.x) + bfhi(a.x) * bfhi(b.x)
          + bflo(a.y) * bflo(b.y) + bfhi(a.y) * bfhi(b.y)
          + bflo(a.z) * bflo(b.z) + bfhi(a.z) * bfhi(b.z)
          + bflo(a.w) * bflo(b.w) + bfhi(a.w) * bfhi(b.w);
  p += __shfl_xor(p, 4);
  p += __shfl_xor(p, 2);
  p += __shfl_xor(p, 1);
  if (wi == 0) out[g] = p;   // [0,E): pos, [E,2E): neg
}

extern "C" void kernel_launch(void* const* d_in, const int* in_sizes, int n_in,
                              void* d_out, int out_size, void* d_ws, size_t ws_size,
                              hipStream_t stream) {
  const float* x  = (const float*)d_in[0];
  const void*  pei = d_in[1];
  const void*  nei = d_in[2];
  const float* W1 = (const float*)d_in[3];
  const float* b1 = (const float*)d_in[4];
  const float* W2 = (const float*)d_in[5];
  const float* b2 = (const float*)d_in[6];
  float* out = (float*)d_out;

  const int       N  = in_sizes[0] / IC1;    // 100000
  const long long E  = in_sizes[1] / 2;      // 1600000
  const int       NB = (N + BNODES - 1) >> BSH;

  // ---- workspace carve (256B-aligned) ----
  char* p = (char*)d_ws;
  auto carve = [&](size_t bytes) { char* r = p; p += ((bytes + 255) & ~(size_t)255); return r; };
  int*   flagbuf = (int*)  carve(8);
  float* dinv    = (float*)carve((size_t)N * 4);
  int*   rowst   = (int*)  carve((size_t)(N + 1) * 4);
  int*   bcnt    = (int*)  carve((size_t)NB * 4);
  int*   gcur0   = (int*)  carve((size_t)NB * 4);
  u32*   binned  = (u32*)  carve((size_t)E * 4);
  u32*   csr     = (u32*)  carve((size_t)E * 4);
  u16*   Wt1     = (u16*)  carve((size_t)128 * OC1 * 2);
  u16*   Wt2     = (u16*)  carve((size_t)128 * OC2 * 2);
  u16*   bufA    = (u16*)  carve((size_t)N * IC1 * 2);    // t1 / t2 (bf16)
  u16*   bufB    = (u16*)  carve((size_t)N * IC1 * 2);    // h1 / z  (bf16)

  const int B = 256;

  // ---- graph structure (shared by both convs) ----
  hipMemsetAsync(bcnt, 0, (size_t)NB * 4, stream);
  hipMemsetAsync(gcur0, 0, (size_t)NB * 4, stream);
  k_detect<<<1, B, 0, stream>>>(pei, E, N, flagbuf);
  k_hist<<<dim3((unsigned)((E + CHH - 1) / CHH)), B, 0, stream>>>(pei, E, flagbuf,
                                                                  bcnt, NB);
  k_bin<<<dim3((unsigned)((E + CHB - 1) / CHB)), B, 0, stream>>>(pei, E, flagbuf,
                                                                 bcnt, gcur0,
                                                                 binned, NB);
  k_fill2<<<dim3(NB), 512, 0, stream>>>(binned, bcnt, dinv, rowst, csr, N, NB);

  // ---- weights ----
  k_prepw<<<dim3((128 * (OC1 + OC2) + B - 1) / B), B, 0, stream>>>(W1, W2, Wt1, Wt2);

  // ---- conv1: t1 = x@W1 -> aggregate -> +b1, relu -> h1 ----
  k_gemm_mfma<OC1, false><<<dim3((N + 127) / 128), B, 0, stream>>>(x, Wt1, bufA, N);
  k_agg<OC1><<<dim3((N + 3) / 4), B, 0, stream>>>(bufA, bufB, dinv, rowst,
                                                  csr, b1, N, 1);

  // ---- conv2: t2 = h1@W2 -> aggregate -> +b2 -> z ----
  k_gemm_mfma<OC2, true><<<dim3((N + 127) / 128), B, 0, stream>>>(bufB, Wt2, bufA, N);
  k_agg<OC2><<<dim3((N + 3) / 4), B, 0, stream>>>(bufA, bufB, dinv, rowst,
                                                  csr, b2, N, 0);

  // ---- decode: pos & neg dot products ----
  long long groups = 2 * E;
  dim3 gD((unsigned)((groups * 8 + B - 1) / B));
  k_decode<<<gD, B, 0, stream>>>(bufB, pei, nei, out, E, flagbuf);
}